// Round 13
// baseline (283.226 us; speedup 1.0000x reference)
//
#include <hip/hip_runtime.h>

#define NN 100000
#define NE 1600000
#define NBUK 1563          // ceil(NN/64) buckets of 64 nodes
#define EB 8192            // edges per scatter block
#define NBLK 782           // gemm1 row-blocks of 128

typedef __attribute__((ext_vector_type(8))) short v8s;
typedef __attribute__((ext_vector_type(4))) float v4f;

__device__ __forceinline__ unsigned short f2bf(float f) {
  unsigned int u = __float_as_uint(f);
  unsigned int r = (u + 0x7FFFu + ((u >> 16) & 1u)) >> 16;
  return (unsigned short)r;
}
__device__ __forceinline__ float bflo(unsigned int w) { return __uint_as_float(w << 16); }
__device__ __forceinline__ float bfhi(unsigned int w) { return __uint_as_float(w & 0xFFFF0000u); }

// ---------------- bucket histogram (391 blocks x 4096 edges) ---------------

__global__ __launch_bounds__(256) void k_hist(const int* __restrict__ dst,
                                              int* __restrict__ hist) {
  __shared__ int lh[NBUK];
  int t = threadIdx.x;
  for (int i = t; i < NBUK; i += 256) lh[i] = 0;
  __syncthreads();
  int base = blockIdx.x * 4096;
  int lim = min(4096, NE - base);
  for (int j = t; j < lim; j += 256) atomicAdd(&lh[dst[base + j] >> 6], 1);
  __syncthreads();
  for (int i = t; i < NBUK; i += 256) {
    int c = lh[i];
    if (c) atomicAdd(&hist[i], c);
  }
}

// single-block exclusive scan: hist -> bbase, gcur (shfl-based)
__global__ __launch_bounds__(256) void k_scanb(const int* __restrict__ hist,
                                               int* __restrict__ bbase,
                                               int* __restrict__ gcur) {
  __shared__ int wsum[4];
  int t = threadIdx.x, w = t >> 6, l = t & 63;
  int carry = 0;
  for (int c = 0; c < (NBUK + 255) / 256; ++c) {
    int i = c * 256 + t;
    int vv = (i < NBUK) ? hist[i] : 0;
    int inc = vv;
#pragma unroll
    for (int o = 1; o < 64; o <<= 1) {
      int uu = __shfl_up(inc, o, 64);
      if (l >= o) inc += uu;
    }
    if (l == 63) wsum[w] = inc;
    __syncthreads();
    int woff = 0;
    for (int j = 0; j < w; ++j) woff += wsum[j];
    int excl = carry + woff + inc - vv;
    if (i < NBUK) { bbase[i] = excl; gcur[i] = excl; }
    int tot = wsum[0] + wsum[1] + wsum[2] + wsum[3];
    __syncthreads();
    carry += tot;
  }
}

// ---------------- bucket scatter (direct claimed writes) -------------------
__global__ __launch_bounds__(256) void k_scatter(const int* __restrict__ src,
                                                 const int* __restrict__ dst,
                                                 int* __restrict__ gcur,
                                                 unsigned int* __restrict__ staged) {
  __shared__ int lhist[NBUK];
  __shared__ int lcur[NBUK];
  __shared__ int gclaim[NBUK];
  int t = threadIdx.x;
  int e0 = blockIdx.x * EB;
  int ecnt = min(EB, NE - e0);
  for (int i = t; i < NBUK; i += 256) { lhist[i] = 0; lcur[i] = 0; }
  __syncthreads();
  for (int j = t; j < ecnt; j += 256) atomicAdd(&lhist[dst[e0 + j] >> 6], 1);
  __syncthreads();
  for (int b = t; b < NBUK; b += 256) {
    int c = lhist[b];
    gclaim[b] = c ? atomicAdd(&gcur[b], c) : 0;
  }
  __syncthreads();
  for (int j = t; j < ecnt; j += 256) {
    int s = src[e0 + j], d = dst[e0 + j];
    int b = d >> 6;
    int lp = atomicAdd(&lcur[b], 1);
    staged[gclaim[b] + lp] = ((unsigned int)s << 6) | (unsigned int)(d & 63);
  }
}

// ---------------- fused: per-bucket sort2 (even blocks) || MFMA gemm1
//                  (odd blocks).  Independent work, one dispatch: sort2's
//                  memory churn fills gemm1's idle (latency-bound) slots.
// gemm1: u = x@W1l^T, v = x@W1r^T (bf16 out); 512 thr, 128 rows/block,
// W staged+converted f32->bf16 in LDS pitch 272B; operands swapped so each
// lane owns 4 consecutive output cols of one x-row -> 8B uint2 stores.
extern __shared__ char smem_dyn[];
__global__ __launch_bounds__(512) void k_s2g1(
    const unsigned int* __restrict__ staged, const int* __restrict__ bbase,
    const int* __restrict__ hist, int* __restrict__ csr,
    int* __restrict__ off, int* __restrict__ deg,
    const float* __restrict__ x, const float* __restrict__ W1l,
    const float* __restrict__ W1r,
    unsigned short* __restrict__ u, unsigned short* __restrict__ v) {
  __shared__ int h64[64], c64[64];
  int b = blockIdx.x;
  int t = threadIdx.x;

  if ((b & 1) == 0) {
    // -------- sort2 role: bucket = b>>1 (0..1562) --------
    int bkt = b >> 1;
    if (t < 64) h64[t] = 0;
    __syncthreads();
    int st = bbase[bkt], cnt = hist[bkt];
    for (int j = t; j < cnt; j += 512) atomicAdd(&h64[staged[st + j] & 63], 1);
    __syncthreads();
    if (t < 64) {
      int vv = h64[t];
      int inc = vv;
      for (int o = 1; o < 64; o <<= 1) {
        int uu = __shfl_up(inc, o, 64);
        if (t >= o) inc += uu;
      }
      int excl = inc - vv;
      c64[t] = excl;
      int node = bkt * 64 + t;
      if (node < NN) { off[node] = st + excl; deg[node] = vv; }
    }
    __syncthreads();
    for (int j = t; j < cnt; j += 512) {
      unsigned pk = staged[st + j];
      int lp = atomicAdd(&c64[pk & 63], 1);
      csr[st + lp] = (int)(pk >> 6);
    }
    return;
  }

  // -------- gemm1 role: row-block mb = b>>1 (0..781) --------
  int mb = b >> 1;
  if (mb >= NBLK) return;
  char* wlds = smem_dyn;
  {
    int rsub = t >> 4, chunk = t & 15;   // rsub 0..31, chunk 0..15
#pragma unroll
    for (int rd = 0; rd < 8; ++rd) {
      int row = rd * 32 + rsub;
      const float* wsrc = (row < 128) ? (W1l + (size_t)row * 128 + chunk * 8)
                                      : (W1r + (size_t)(row - 128) * 128 + chunk * 8);
      float4 f0 = *(const float4*)wsrc;
      float4 f1 = *(const float4*)(wsrc + 4);
      unsigned d0 = (unsigned)f2bf(f0.x) | ((unsigned)f2bf(f0.y) << 16);
      unsigned d1 = (unsigned)f2bf(f0.z) | ((unsigned)f2bf(f0.w) << 16);
      unsigned d2 = (unsigned)f2bf(f1.x) | ((unsigned)f2bf(f1.y) << 16);
      unsigned d3 = (unsigned)f2bf(f1.z) | ((unsigned)f2bf(f1.w) << 16);
      *(uint4*)(wlds + row * 272 + chunk * 16) = make_uint4(d0, d1, d2, d3);
    }
  }

  int wave = t >> 6, l = t & 63;
  int m0 = mb * 128 + wave * 16;
  int lr = l & 15, kq = l >> 4;
  int rowc = min(m0 + lr, NN - 1);

  v8s a[4];
#pragma unroll
  for (int ks = 0; ks < 4; ++ks) {
    const float* xp = x + (size_t)rowc * 128 + ks * 32 + kq * 8;
    float4 f0 = *(const float4*)xp;
    float4 f1 = *(const float4*)(xp + 4);
    v8s tv;
    tv[0] = (short)f2bf(f0.x); tv[1] = (short)f2bf(f0.y);
    tv[2] = (short)f2bf(f0.z); tv[3] = (short)f2bf(f0.w);
    tv[4] = (short)f2bf(f1.x); tv[5] = (short)f2bf(f1.y);
    tv[6] = (short)f2bf(f1.z); tv[7] = (short)f2bf(f1.w);
    a[ks] = tv;
  }

  __syncthreads();

  v4f acc[16];
#pragma unroll
  for (int nt = 0; nt < 16; ++nt) acc[nt] = (v4f){0.f, 0.f, 0.f, 0.f};

#pragma unroll
  for (int nt = 0; nt < 16; ++nt) {
    const char* wrow = wlds + (nt * 16 + lr) * 272;
#pragma unroll
    for (int ks = 0; ks < 4; ++ks) {
      v8s bb = *(const v8s*)(wrow + ks * 64 + kq * 16);
      acc[nt] = __builtin_amdgcn_mfma_f32_16x16x32_bf16(bb, a[ks], acc[nt], 0, 0, 0);
    }
  }

  if (m0 + lr < NN) {
    size_t rowb = (size_t)(m0 + lr) * 128;
#pragma unroll
    for (int nt = 0; nt < 16; ++nt) {
      unsigned lo = (unsigned)f2bf(acc[nt][0]) | ((unsigned)f2bf(acc[nt][1]) << 16);
      unsigned hi = (unsigned)f2bf(acc[nt][2]) | ((unsigned)f2bf(acc[nt][3]) << 16);
      int col = (nt & 7) * 16 + kq * 4;
      if (nt < 8) *(uint2*)(u + rowb + col) = make_uint2(lo, hi);
      else        *(uint2*)(v + rowb + col) = make_uint2(lo, hi);
    }
  }
}

// ---------------- fused: mean-agg(u) + v + b1 -> relu -> h1; p=h1@W2l^T,
//                  r=h1@W2r^T.  Pair layout (40 VGPR, measured optimum).
__global__ __launch_bounds__(256) void k_agg(
    const unsigned short* __restrict__ u, const unsigned short* __restrict__ v,
    const int* __restrict__ csr, const int* __restrict__ off, const int* __restrict__ deg,
    const float* __restrict__ b1,
    const float* __restrict__ W2l, const float* __restrict__ W2r,
    float* __restrict__ p, float* __restrict__ r) {
  int wid = (blockIdx.x * blockDim.x + threadIdx.x) >> 6;  // node
  int l = threadIdx.x & 63;
  if (wid >= NN) return;
  int cnt = deg[wid], st = off[wid];
  int half = l >> 5;
  int dpos = l & 31;
  const char* ubase = (const char*)u + (dpos << 3);

  // hoisted epilogue operands (overlap with gather latency)
  uint2 vw = *(const uint2*)((const char*)v + ((size_t)wid << 8) + (dpos << 3));
  float4 bb = *(const float4*)(b1 + 4 * dpos);
  const float* Wbase = half ? W2r : W2l;
  float4 wv[4];
#pragma unroll
  for (int o = 0; o < 4; ++o) wv[o] = *(const float4*)(Wbase + o * 128 + 4 * dpos);

  float a0 = 0.f, a1 = 0.f, a2 = 0.f, a3 = 0.f;

#define LOADW(W, S) uint2 W = *(const uint2*)(ubase + ((size_t)((unsigned)(S) << 8)))
#define ACCW(W) { a0 += bflo(W.x); a1 += bfhi(W.x); a2 += bflo(W.y); a3 += bfhi(W.y); }

  for (int base = 0; base < cnt; base += 64) {
    int nloc = min(64, cnt - base);
    int idx = 0;
    if (l < nloc) idx = csr[st + base + l];
    int npair = nloc >> 1;
    int e = 0;
    for (; e + 8 <= npair; e += 8) {
      int s0 = __shfl(idx, 2 * e + half, 64);
      int s1 = __shfl(idx, 2 * (e + 1) + half, 64);
      int s2 = __shfl(idx, 2 * (e + 2) + half, 64);
      int s3 = __shfl(idx, 2 * (e + 3) + half, 64);
      int s4 = __shfl(idx, 2 * (e + 4) + half, 64);
      int s5 = __shfl(idx, 2 * (e + 5) + half, 64);
      int s6 = __shfl(idx, 2 * (e + 6) + half, 64);
      int s7 = __shfl(idx, 2 * (e + 7) + half, 64);
      LOADW(w0, s0);
      LOADW(w1, s1);
      LOADW(w2, s2);
      LOADW(w3, s3);
      LOADW(w4, s4);
      LOADW(w5, s5);
      LOADW(w6, s6);
      LOADW(w7, s7);
      ACCW(w0); ACCW(w1); ACCW(w2); ACCW(w3);
      ACCW(w4); ACCW(w5); ACCW(w6); ACCW(w7);
    }
    for (; e + 4 <= npair; e += 4) {
      int s0 = __shfl(idx, 2 * e + half, 64);
      int s1 = __shfl(idx, 2 * (e + 1) + half, 64);
      int s2 = __shfl(idx, 2 * (e + 2) + half, 64);
      int s3 = __shfl(idx, 2 * (e + 3) + half, 64);
      LOADW(w0, s0);
      LOADW(w1, s1);
      LOADW(w2, s2);
      LOADW(w3, s3);
      ACCW(w0); ACCW(w1); ACCW(w2); ACCW(w3);
    }
    for (; e < npair; ++e) {
      int s = __shfl(idx, 2 * e + half, 64);
      LOADW(w, s);
      ACCW(w);
    }
    if (nloc & 1) {
      int s = __shfl(idx, nloc - 1, 64);
      if (half == 0) {
        LOADW(w, s);
        ACCW(w);
      }
    }
  }
#undef LOADW
#undef ACCW

  // merge the two edge-halves; afterwards both halves hold full sums
  a0 += __shfl_xor(a0, 32, 64);
  a1 += __shfl_xor(a1, 32, 64);
  a2 += __shfl_xor(a2, 32, 64);
  a3 += __shfl_xor(a3, 32, 64);

  float inv = 1.f / (float)max(cnt, 1);
  float h0 = fmaxf(fmaf(a0, inv, bflo(vw.x) + bb.x), 0.f);
  float h1 = fmaxf(fmaf(a1, inv, bfhi(vw.x) + bb.y), 0.f);
  float h2 = fmaxf(fmaf(a2, inv, bflo(vw.y) + bb.z), 0.f);
  float h3 = fmaxf(fmaf(a3, inv, bfhi(vw.y) + bb.w), 0.f);

  // half 0 -> p = h@W2l^T ; half 1 -> r = h@W2r^T  (4 outputs each)
  float t0 = h0 * wv[0].x + h1 * wv[0].y + h2 * wv[0].z + h3 * wv[0].w;
  float t1 = h0 * wv[1].x + h1 * wv[1].y + h2 * wv[1].z + h3 * wv[1].w;
  float t2 = h0 * wv[2].x + h1 * wv[2].y + h2 * wv[2].z + h3 * wv[2].w;
  float t3 = h0 * wv[3].x + h1 * wv[3].y + h2 * wv[3].z + h3 * wv[3].w;
  // multi-value butterfly: after stage 2, lane (l&3)==o holds output o
  float v01 = (l & 1) ? t1 : t0;
  float w01 = __shfl_xor((l & 1) ? t0 : t1, 1, 64);
  float r01 = v01 + w01;
  float v23 = (l & 1) ? t3 : t2;
  float w23 = __shfl_xor((l & 1) ? t2 : t3, 1, 64);
  float r23 = v23 + w23;
  float vq = (l & 2) ? r23 : r01;
  float wq = __shfl_xor((l & 2) ? r01 : r23, 2, 64);
  float rr = vq + wq;
  rr += __shfl_xor(rr, 4, 64);
  rr += __shfl_xor(rr, 8, 64);
  rr += __shfl_xor(rr, 16, 64);
  float* outp = half ? r : p;
  if (dpos < 4) outp[(size_t)wid * 4 + dpos] = rr;
}

// ---------------- layer-2 aggregation + final linear --------------------
__global__ __launch_bounds__(256) void k_final(
    const float* __restrict__ p, const float* __restrict__ r,
    const int* __restrict__ csr, const int* __restrict__ off,
    const int* __restrict__ deg,
    const float* __restrict__ b2,
    const float* __restrict__ Wlin, const float* __restrict__ blin,
    float* __restrict__ out) {
  int gid = blockIdx.x * blockDim.x + threadIdx.x;
  int node = gid >> 3;
  int sl = gid & 7;
  if (node >= NN) return;
  int cnt = deg[node], st = off[node];
  int l = threadIdx.x & 63;

  float a0 = 0.f, a1 = 0.f, a2 = 0.f, a3 = 0.f;
  for (int e = sl; e < cnt; e += 8) {
    int s = csr[st + e];
    const float4 pv = *(const float4*)(p + (size_t)s * 4);
    a0 += pv.x; a1 += pv.y; a2 += pv.z; a3 += pv.w;
  }
  float v01 = (l & 1) ? a1 : a0;
  float w01 = __shfl_xor((l & 1) ? a0 : a1, 1, 64);
  float r01 = v01 + w01;
  float v23 = (l & 1) ? a3 : a2;
  float w23 = __shfl_xor((l & 1) ? a2 : a3, 1, 64);
  float r23 = v23 + w23;
  float vq = (l & 2) ? r23 : r01;
  float wq = __shfl_xor((l & 2) ? r01 : r23, 2, 64);
  float rr = vq + wq;
  rr += __shfl_xor(rr, 4, 64);
  int o = sl & 3;
  float inv = 1.f / (float)max(cnt, 1);
  float g = rr * inv + b2[o] + r[(size_t)node * 4 + o];
  float t0 = g * Wlin[o];
  float t1 = g * Wlin[4 + o];
  float vv = (l & 1) ? t1 : t0;
  float ww = __shfl_xor((l & 1) ? t0 : t1, 1, 64);
  float q = vv + ww;
  q += __shfl_xor(q, 2, 64);
  if (sl < 2) out[(size_t)node * 2 + sl] = q + blin[sl];
}

// ---------------- launch ----------------

extern "C" void kernel_launch(void* const* d_in, const int* in_sizes, int n_in,
                              void* d_out, int out_size, void* d_ws, size_t ws_size,
                              hipStream_t stream) {
  const float* x    = (const float*)d_in[0];
  const int*   ei   = (const int*)d_in[1];
  const int*   src  = ei;
  const int*   dst  = ei + NE;
  const float* W1l  = (const float*)d_in[2];
  const float* b1   = (const float*)d_in[3];
  const float* W1r  = (const float*)d_in[4];
  const float* W2l  = (const float*)d_in[5];
  const float* b2   = (const float*)d_in[6];
  const float* W2r  = (const float*)d_in[7];
  const float* Wlin = (const float*)d_in[8];
  const float* blin = (const float*)d_in[9];
  float* out = (float*)d_out;

  char* w = (char*)d_ws;
  size_t o = 0;
  auto alloc = [&](size_t bytes) {
    void* pp = (void*)(w + o);
    o = (o + bytes + 255) & ~(size_t)255;
    return pp;
  };
  int* hist  = (int*)alloc(NBUK * 4);
  int* bbase = (int*)alloc(NBUK * 4);
  int* gcur  = (int*)alloc(NBUK * 4);
  unsigned int* staged = (unsigned int*)alloc((size_t)NE * 4);
  int* csr   = (int*)alloc((size_t)NE * 4);
  int* offs  = (int*)alloc(NN * 4);
  int* deg   = (int*)alloc(NN * 4);
  unsigned short* ubuf  = (unsigned short*)alloc((size_t)NN * 128 * 2);
  unsigned short* vbuf  = (unsigned short*)alloc((size_t)NN * 128 * 2);
  float* pbuf = (float*)alloc((size_t)NN * 4 * 4);
  float* rbuf = (float*)alloc((size_t)NN * 4 * 4);

  const size_t gemm1_lds = 256 * 272;   // 69632 B

  hipMemsetAsync(hist, 0, NBUK * 4, stream);
  hipLaunchKernelGGL(k_hist,  dim3((NE + 4095) / 4096), dim3(256), 0, stream, dst, hist);
  hipLaunchKernelGGL(k_scanb, dim3(1), dim3(256), 0, stream, hist, bbase, gcur);
  hipLaunchKernelGGL(k_scatter, dim3((NE + EB - 1) / EB), dim3(256), 0, stream,
                     src, dst, gcur, staged);
  hipLaunchKernelGGL(k_s2g1, dim3(NBUK * 2), dim3(512), gemm1_lds, stream,
                     staged, bbase, hist, csr, offs, deg, x, W1l, W1r, ubuf, vbuf);
  hipLaunchKernelGGL(k_agg,   dim3((NN * 64 + 255) / 256), dim3(256), 0, stream,
                     ubuf, vbuf, csr, offs, deg, b1, W2l, W2r, pbuf, rbuf);
  hipLaunchKernelGGL(k_final, dim3((NN * 8 + 255) / 256), dim3(256), 0, stream,
                     pbuf, rbuf, csr, offs, deg, b2, Wlin, blin, out);
}

// Round 14
// 274.357 us; speedup vs baseline: 1.0323x; 1.0323x over previous
//
#include <hip/hip_runtime.h>

#define NN 100000
#define NE 1600000
#define NBUK 1563          // ceil(NN/64) buckets of 64 nodes
#define EB 8192            // edges per scatter block

typedef __attribute__((ext_vector_type(8))) short v8s;
typedef __attribute__((ext_vector_type(4))) float v4f;

__device__ __forceinline__ unsigned short f2bf(float f) {
  unsigned int u = __float_as_uint(f);
  unsigned int r = (u + 0x7FFFu + ((u >> 16) & 1u)) >> 16;
  return (unsigned short)r;
}
__device__ __forceinline__ float bflo(unsigned int w) { return __uint_as_float(w << 16); }
__device__ __forceinline__ float bfhi(unsigned int w) { return __uint_as_float(w & 0xFFFF0000u); }

// ---------------- bucket histogram (391 blocks x 4096 edges) ---------------
// Also zeroes gtot (used by k_claim, a later stream-ordered dispatch).
__global__ __launch_bounds__(256) void k_hist(const int* __restrict__ dst,
                                              int* __restrict__ hist,
                                              int* __restrict__ gtot) {
  __shared__ int lh[NBUK];
  int t = threadIdx.x;
  if (blockIdx.x == 0 && t == 0) *gtot = 0;
  for (int i = t; i < NBUK; i += 256) lh[i] = 0;
  __syncthreads();
  int base = blockIdx.x * 4096;
  int lim = min(4096, NE - base);
  for (int j = t; j < lim; j += 256) atomicAdd(&lh[dst[base + j] >> 6], 1);
  __syncthreads();
  for (int i = t; i < NBUK; i += 256) {
    int c = lh[i];
    if (c) atomicAdd(&hist[i], c);
  }
}

// ---------------- parallel window allocation (replaces serial 1-block scan)
// Bucket windows need only be DISJOINT, not ordered: bbase[i] via one
// global atomic each. 1563 atomics across 7 blocks vs 7 serial chunks on
// a single CU.
__global__ __launch_bounds__(256) void k_claim(const int* __restrict__ hist,
                                               int* __restrict__ gtot,
                                               int* __restrict__ bbase,
                                               int* __restrict__ gcur) {
  int i = blockIdx.x * 256 + threadIdx.x;
  if (i < NBUK) {
    int c = hist[i];
    int b = atomicAdd(gtot, c);
    bbase[i] = b;
    gcur[i] = b;
  }
}

// ---------------- bucket scatter (direct claimed writes) -------------------
__global__ __launch_bounds__(256) void k_scatter(const int* __restrict__ src,
                                                 const int* __restrict__ dst,
                                                 int* __restrict__ gcur,
                                                 unsigned int* __restrict__ staged) {
  __shared__ int lhist[NBUK];
  __shared__ int lcur[NBUK];
  __shared__ int gclaim[NBUK];
  int t = threadIdx.x;
  int e0 = blockIdx.x * EB;
  int ecnt = min(EB, NE - e0);
  for (int i = t; i < NBUK; i += 256) { lhist[i] = 0; lcur[i] = 0; }
  __syncthreads();
  for (int j = t; j < ecnt; j += 256) atomicAdd(&lhist[dst[e0 + j] >> 6], 1);
  __syncthreads();
  for (int b = t; b < NBUK; b += 256) {
    int c = lhist[b];
    gclaim[b] = c ? atomicAdd(&gcur[b], c) : 0;
  }
  __syncthreads();
  for (int j = t; j < ecnt; j += 256) {
    int s = src[e0 + j], d = dst[e0 + j];
    int b = d >> 6;
    int lp = atomicAdd(&lcur[b], 1);
    staged[gclaim[b] + lp] = ((unsigned int)s << 6) | (unsigned int)(d & 63);
  }
}

// ---------------- per-bucket radix pass 2: staged -> CSR + off + deg -------
__global__ __launch_bounds__(256) void k_sort2(const unsigned int* __restrict__ staged,
                                               const int* __restrict__ bbase,
                                               const int* __restrict__ hist,
                                               int* __restrict__ csr,
                                               int* __restrict__ off,
                                               int* __restrict__ deg) {
  __shared__ int h64[64], c64[64];
  int bkt = blockIdx.x, t = threadIdx.x;
  if (t < 64) h64[t] = 0;
  __syncthreads();
  int st = bbase[bkt], cnt = hist[bkt];
  for (int j = t; j < cnt; j += 256) atomicAdd(&h64[staged[st + j] & 63], 1);
  __syncthreads();
  if (t < 64) {
    int v = h64[t];
    int inc = v;
    for (int o = 1; o < 64; o <<= 1) {
      int uu = __shfl_up(inc, o, 64);
      if (t >= o) inc += uu;
    }
    int excl = inc - v;
    c64[t] = excl;
    int node = bkt * 64 + t;
    if (node < NN) { off[node] = st + excl; deg[node] = v; }
  }
  __syncthreads();
  for (int j = t; j < cnt; j += 256) {
    unsigned pk = staged[st + j];
    int lp = atomicAdd(&c64[pk & 63], 1);
    csr[st + lp] = (int)(pk >> 6);
  }
}

// ---------------- MFMA GEMM: u = x@W1l^T, v = x@W1r^T (bf16 out) ----------
// 512-thread blocks, 128 rows/block; W staged+converted f32->bf16 in LDS
// (pitch 272B). Operands swapped (A=W, B=x): lane owns 4 consecutive output
// cols of one x-row -> 8B uint2 stores.  (R9 measured-best configuration.)
extern __shared__ char smem_dyn[];
__global__ __launch_bounds__(512) void k_gemm1(
    const float* __restrict__ x, const float* __restrict__ W1l,
    const float* __restrict__ W1r,
    unsigned short* __restrict__ u, unsigned short* __restrict__ v) {
  char* wlds = smem_dyn;
  int t = threadIdx.x;
  {
    int rsub = t >> 4, chunk = t & 15;   // rsub 0..31, chunk 0..15
#pragma unroll
    for (int rd = 0; rd < 8; ++rd) {
      int row = rd * 32 + rsub;
      const float* wsrc = (row < 128) ? (W1l + (size_t)row * 128 + chunk * 8)
                                      : (W1r + (size_t)(row - 128) * 128 + chunk * 8);
      float4 f0 = *(const float4*)wsrc;
      float4 f1 = *(const float4*)(wsrc + 4);
      unsigned d0 = (unsigned)f2bf(f0.x) | ((unsigned)f2bf(f0.y) << 16);
      unsigned d1 = (unsigned)f2bf(f0.z) | ((unsigned)f2bf(f0.w) << 16);
      unsigned d2 = (unsigned)f2bf(f1.x) | ((unsigned)f2bf(f1.y) << 16);
      unsigned d3 = (unsigned)f2bf(f1.z) | ((unsigned)f2bf(f1.w) << 16);
      *(uint4*)(wlds + row * 272 + chunk * 16) = make_uint4(d0, d1, d2, d3);
    }
  }

  int wave = t >> 6, l = t & 63;
  int m0 = blockIdx.x * 128 + wave * 16;
  int lr = l & 15, kq = l >> 4;
  int rowc = min(m0 + lr, NN - 1);

  v8s a[4];
#pragma unroll
  for (int ks = 0; ks < 4; ++ks) {
    const float* xp = x + (size_t)rowc * 128 + ks * 32 + kq * 8;
    float4 f0 = *(const float4*)xp;
    float4 f1 = *(const float4*)(xp + 4);
    v8s tv;
    tv[0] = (short)f2bf(f0.x); tv[1] = (short)f2bf(f0.y);
    tv[2] = (short)f2bf(f0.z); tv[3] = (short)f2bf(f0.w);
    tv[4] = (short)f2bf(f1.x); tv[5] = (short)f2bf(f1.y);
    tv[6] = (short)f2bf(f1.z); tv[7] = (short)f2bf(f1.w);
    a[ks] = tv;
  }

  __syncthreads();

  v4f acc[16];
#pragma unroll
  for (int nt = 0; nt < 16; ++nt) acc[nt] = (v4f){0.f, 0.f, 0.f, 0.f};

#pragma unroll
  for (int nt = 0; nt < 16; ++nt) {
    const char* wrow = wlds + (nt * 16 + lr) * 272;
#pragma unroll
    for (int ks = 0; ks < 4; ++ks) {
      v8s b = *(const v8s*)(wrow + ks * 64 + kq * 16);
      acc[nt] = __builtin_amdgcn_mfma_f32_16x16x32_bf16(b, a[ks], acc[nt], 0, 0, 0);
    }
  }

  if (m0 + lr < NN) {
    size_t rowb = (size_t)(m0 + lr) * 128;
#pragma unroll
    for (int nt = 0; nt < 16; ++nt) {
      unsigned lo = (unsigned)f2bf(acc[nt][0]) | ((unsigned)f2bf(acc[nt][1]) << 16);
      unsigned hi = (unsigned)f2bf(acc[nt][2]) | ((unsigned)f2bf(acc[nt][3]) << 16);
      int col = (nt & 7) * 16 + kq * 4;
      if (nt < 8) *(uint2*)(u + rowb + col) = make_uint2(lo, hi);
      else        *(uint2*)(v + rowb + col) = make_uint2(lo, hi);
    }
  }
}

// ---------------- fused: mean-agg(u) + v + b1 -> relu -> h1; p=h1@W2l^T,
//                  r=h1@W2r^T.  Pair layout (40 VGPR, measured optimum).
__global__ __launch_bounds__(256) void k_agg(
    const unsigned short* __restrict__ u, const unsigned short* __restrict__ v,
    const int* __restrict__ csr, const int* __restrict__ off, const int* __restrict__ deg,
    const float* __restrict__ b1,
    const float* __restrict__ W2l, const float* __restrict__ W2r,
    float* __restrict__ p, float* __restrict__ r) {
  int wid = (blockIdx.x * blockDim.x + threadIdx.x) >> 6;  // node
  int l = threadIdx.x & 63;
  if (wid >= NN) return;
  int cnt = deg[wid], st = off[wid];
  int half = l >> 5;
  int dpos = l & 31;
  const char* ubase = (const char*)u + (dpos << 3);

  // hoisted epilogue operands (overlap with gather latency)
  uint2 vw = *(const uint2*)((const char*)v + ((size_t)wid << 8) + (dpos << 3));
  float4 bb = *(const float4*)(b1 + 4 * dpos);
  const float* Wbase = half ? W2r : W2l;
  float4 wv[4];
#pragma unroll
  for (int o = 0; o < 4; ++o) wv[o] = *(const float4*)(Wbase + o * 128 + 4 * dpos);

  float a0 = 0.f, a1 = 0.f, a2 = 0.f, a3 = 0.f;

#define LOADW(W, S) uint2 W = *(const uint2*)(ubase + ((size_t)((unsigned)(S) << 8)))
#define ACCW(W) { a0 += bflo(W.x); a1 += bfhi(W.x); a2 += bflo(W.y); a3 += bfhi(W.y); }

  for (int base = 0; base < cnt; base += 64) {
    int nloc = min(64, cnt - base);
    int idx = 0;
    if (l < nloc) idx = csr[st + base + l];
    int npair = nloc >> 1;
    int e = 0;
    for (; e + 8 <= npair; e += 8) {
      int s0 = __shfl(idx, 2 * e + half, 64);
      int s1 = __shfl(idx, 2 * (e + 1) + half, 64);
      int s2 = __shfl(idx, 2 * (e + 2) + half, 64);
      int s3 = __shfl(idx, 2 * (e + 3) + half, 64);
      int s4 = __shfl(idx, 2 * (e + 4) + half, 64);
      int s5 = __shfl(idx, 2 * (e + 5) + half, 64);
      int s6 = __shfl(idx, 2 * (e + 6) + half, 64);
      int s7 = __shfl(idx, 2 * (e + 7) + half, 64);
      LOADW(w0, s0);
      LOADW(w1, s1);
      LOADW(w2, s2);
      LOADW(w3, s3);
      LOADW(w4, s4);
      LOADW(w5, s5);
      LOADW(w6, s6);
      LOADW(w7, s7);
      ACCW(w0); ACCW(w1); ACCW(w2); ACCW(w3);
      ACCW(w4); ACCW(w5); ACCW(w6); ACCW(w7);
    }
    for (; e + 4 <= npair; e += 4) {
      int s0 = __shfl(idx, 2 * e + half, 64);
      int s1 = __shfl(idx, 2 * (e + 1) + half, 64);
      int s2 = __shfl(idx, 2 * (e + 2) + half, 64);
      int s3 = __shfl(idx, 2 * (e + 3) + half, 64);
      LOADW(w0, s0);
      LOADW(w1, s1);
      LOADW(w2, s2);
      LOADW(w3, s3);
      ACCW(w0); ACCW(w1); ACCW(w2); ACCW(w3);
    }
    for (; e < npair; ++e) {
      int s = __shfl(idx, 2 * e + half, 64);
      LOADW(w, s);
      ACCW(w);
    }
    if (nloc & 1) {
      int s = __shfl(idx, nloc - 1, 64);
      if (half == 0) {
        LOADW(w, s);
        ACCW(w);
      }
    }
  }
#undef LOADW
#undef ACCW

  // merge the two edge-halves; afterwards both halves hold full sums
  a0 += __shfl_xor(a0, 32, 64);
  a1 += __shfl_xor(a1, 32, 64);
  a2 += __shfl_xor(a2, 32, 64);
  a3 += __shfl_xor(a3, 32, 64);

  float inv = 1.f / (float)max(cnt, 1);
  float h0 = fmaxf(fmaf(a0, inv, bflo(vw.x) + bb.x), 0.f);
  float h1 = fmaxf(fmaf(a1, inv, bfhi(vw.x) + bb.y), 0.f);
  float h2 = fmaxf(fmaf(a2, inv, bflo(vw.y) + bb.z), 0.f);
  float h3 = fmaxf(fmaf(a3, inv, bfhi(vw.y) + bb.w), 0.f);

  // half 0 -> p = h@W2l^T ; half 1 -> r = h@W2r^T  (4 outputs each)
  float t0 = h0 * wv[0].x + h1 * wv[0].y + h2 * wv[0].z + h3 * wv[0].w;
  float t1 = h0 * wv[1].x + h1 * wv[1].y + h2 * wv[1].z + h3 * wv[1].w;
  float t2 = h0 * wv[2].x + h1 * wv[2].y + h2 * wv[2].z + h3 * wv[2].w;
  float t3 = h0 * wv[3].x + h1 * wv[3].y + h2 * wv[3].z + h3 * wv[3].w;
  // multi-value butterfly: after stage 2, lane (l&3)==o holds output o
  float v01 = (l & 1) ? t1 : t0;
  float w01 = __shfl_xor((l & 1) ? t0 : t1, 1, 64);
  float r01 = v01 + w01;
  float v23 = (l & 1) ? t3 : t2;
  float w23 = __shfl_xor((l & 1) ? t2 : t3, 1, 64);
  float r23 = v23 + w23;
  float vq = (l & 2) ? r23 : r01;
  float wq = __shfl_xor((l & 2) ? r01 : r23, 2, 64);
  float rr = vq + wq;
  rr += __shfl_xor(rr, 4, 64);
  rr += __shfl_xor(rr, 8, 64);
  rr += __shfl_xor(rr, 16, 64);
  float* outp = half ? r : p;
  if (dpos < 4) outp[(size_t)wid * 4 + dpos] = rr;
}

// ---------------- layer-2 aggregation + final linear --------------------
__global__ __launch_bounds__(256) void k_final(
    const float* __restrict__ p, const float* __restrict__ r,
    const int* __restrict__ csr, const int* __restrict__ off,
    const int* __restrict__ deg,
    const float* __restrict__ b2,
    const float* __restrict__ Wlin, const float* __restrict__ blin,
    float* __restrict__ out) {
  int gid = blockIdx.x * blockDim.x + threadIdx.x;
  int node = gid >> 3;
  int sl = gid & 7;
  if (node >= NN) return;
  int cnt = deg[node], st = off[node];
  int l = threadIdx.x & 63;

  float a0 = 0.f, a1 = 0.f, a2 = 0.f, a3 = 0.f;
  for (int e = sl; e < cnt; e += 8) {
    int s = csr[st + e];
    const float4 pv = *(const float4*)(p + (size_t)s * 4);
    a0 += pv.x; a1 += pv.y; a2 += pv.z; a3 += pv.w;
  }
  float v01 = (l & 1) ? a1 : a0;
  float w01 = __shfl_xor((l & 1) ? a0 : a1, 1, 64);
  float r01 = v01 + w01;
  float v23 = (l & 1) ? a3 : a2;
  float w23 = __shfl_xor((l & 1) ? a2 : a3, 1, 64);
  float r23 = v23 + w23;
  float vq = (l & 2) ? r23 : r01;
  float wq = __shfl_xor((l & 2) ? r01 : r23, 2, 64);
  float rr = vq + wq;
  rr += __shfl_xor(rr, 4, 64);
  int o = sl & 3;
  float inv = 1.f / (float)max(cnt, 1);
  float g = rr * inv + b2[o] + r[(size_t)node * 4 + o];
  float t0 = g * Wlin[o];
  float t1 = g * Wlin[4 + o];
  float vv = (l & 1) ? t1 : t0;
  float ww = __shfl_xor((l & 1) ? t0 : t1, 1, 64);
  float q = vv + ww;
  q += __shfl_xor(q, 2, 64);
  if (sl < 2) out[(size_t)node * 2 + sl] = q + blin[sl];
}

// ---------------- launch ----------------

extern "C" void kernel_launch(void* const* d_in, const int* in_sizes, int n_in,
                              void* d_out, int out_size, void* d_ws, size_t ws_size,
                              hipStream_t stream) {
  const float* x    = (const float*)d_in[0];
  const int*   ei   = (const int*)d_in[1];
  const int*   src  = ei;
  const int*   dst  = ei + NE;
  const float* W1l  = (const float*)d_in[2];
  const float* b1   = (const float*)d_in[3];
  const float* W1r  = (const float*)d_in[4];
  const float* W2l  = (const float*)d_in[5];
  const float* b2   = (const float*)d_in[6];
  const float* W2r  = (const float*)d_in[7];
  const float* Wlin = (const float*)d_in[8];
  const float* blin = (const float*)d_in[9];
  float* out = (float*)d_out;

  char* w = (char*)d_ws;
  size_t o = 0;
  auto alloc = [&](size_t bytes) {
    void* pp = (void*)(w + o);
    o = (o + bytes + 255) & ~(size_t)255;
    return pp;
  };
  int* hist  = (int*)alloc(NBUK * 4);
  int* gtot  = (int*)alloc(4);
  int* bbase = (int*)alloc(NBUK * 4);
  int* gcur  = (int*)alloc(NBUK * 4);
  unsigned int* staged = (unsigned int*)alloc((size_t)NE * 4);
  int* csr   = (int*)alloc((size_t)NE * 4);
  int* offs  = (int*)alloc(NN * 4);
  int* deg   = (int*)alloc(NN * 4);
  unsigned short* ubuf  = (unsigned short*)alloc((size_t)NN * 128 * 2);
  unsigned short* vbuf  = (unsigned short*)alloc((size_t)NN * 128 * 2);
  float* pbuf = (float*)alloc((size_t)NN * 4 * 4);
  float* rbuf = (float*)alloc((size_t)NN * 4 * 4);

  const size_t gemm1_lds = 256 * 272;   // 69632 B

  hipMemsetAsync(hist, 0, NBUK * 4, stream);
  hipLaunchKernelGGL(k_hist,  dim3((NE + 4095) / 4096), dim3(256), 0, stream,
                     dst, hist, gtot);
  hipLaunchKernelGGL(k_claim, dim3((NBUK + 255) / 256), dim3(256), 0, stream,
                     hist, gtot, bbase, gcur);
  hipLaunchKernelGGL(k_scatter, dim3((NE + EB - 1) / EB), dim3(256), 0, stream,
                     src, dst, gcur, staged);
  hipLaunchKernelGGL(k_sort2, dim3(NBUK), dim3(256), 0, stream,
                     staged, bbase, hist, csr, offs, deg);
  hipLaunchKernelGGL(k_gemm1, dim3((NN + 127) / 128), dim3(512), gemm1_lds, stream,
                     x, W1l, W1r, ubuf, vbuf);
  hipLaunchKernelGGL(k_agg,   dim3((NN * 64 + 255) / 256), dim3(256), 0, stream,
                     ubuf, vbuf, csr, offs, deg, b1, W2l, W2r, pbuf, rbuf);
  hipLaunchKernelGGL(k_final, dim3((NN * 8 + 255) / 256), dim3(256), 0, stream,
                     pbuf, rbuf, csr, offs, deg, b2, Wlin, blin, out);
}